// Round 4
// baseline (268.847 us; speedup 1.0000x reference)
//
#include <hip/hip_runtime.h>

#define B_   8
#define T_   4096
#define D_   1024
#define E_   100
#define EP_  128
#define NTOK (B_*T_)
#define TC_  2            // t-chunks in k_feat

typedef short bf16x8 __attribute__((ext_vector_type(8)));
typedef float f32x4  __attribute__((ext_vector_type(4)));

__device__ __forceinline__ float b2f(unsigned int u){
    union { unsigned int i; float f; } v; v.i = u << 16; return v.f;
}
__device__ __forceinline__ unsigned short f2b(float f){
    union { float f; unsigned int i; } v; v.f = f;
    unsigned int x = v.i;
    return (unsigned short)((x + 0x7fffu + ((x >> 16) & 1u)) >> 16);
}

// ---------------- K1: normalize centroids (fp32 in) -> cn[EP_][D_] bf16 --------
__global__ __launch_bounds__(256) void k_cnorm(const float* __restrict__ cent,
                                               unsigned short* __restrict__ cn){
    const int e = blockIdx.x, tid = threadIdx.x;
    if (e >= E_){
        ((uint2*)(cn + (size_t)e*D_))[tid] = make_uint2(0u, 0u);
        return;
    }
    float4 x = ((const float4*)(cent + (size_t)e*D_))[tid];
    float ss = x.x*x.x + x.y*x.y + x.z*x.z + x.w*x.w;
    __shared__ float red[256];
    red[tid] = ss; __syncthreads();
    for (int s = 128; s > 0; s >>= 1){ if (tid < s) red[tid] += red[tid+s]; __syncthreads(); }
    float inv = 1.0f / fmaxf(sqrtf(red[0]), 1e-12f);
    unsigned int lo = (unsigned int)f2b(x.x*inv) | ((unsigned int)f2b(x.y*inv) << 16);
    unsigned int hi = (unsigned int)f2b(x.z*inv) | ((unsigned int)f2b(x.w*inv) << 16);
    ((uint2*)(cn + (size_t)e*D_))[tid] = make_uint2(lo, hi);
}

// ---------------- K2: sim GEMM + register softmax + coalesced pT ---------------
// grid = NTOK/64 = 512 blocks, 256 threads. Tile: 64 tokens x 128 entities.
__global__ __launch_bounds__(256) void k_sim(const float* __restrict__ tokens,
                                             const unsigned short* __restrict__ cn,
                                             float* __restrict__ out_assign,
                                             unsigned short* __restrict__ pT){
    const int tid = threadIdx.x;
    const int t0  = blockIdx.x * 64;
    const int bb  = t0 >> 12;
    const int tl0 = t0 & (T_ - 1);

    __shared__ __align__(16) unsigned short lds_a[64*72];
    __shared__ __align__(16) unsigned short lds_b[128*72];   // K-loop B-tile; later pT transpose tile [128e][72]
    __shared__ float red[256];
    __shared__ float srow[64];
    __shared__ float cm[64][2];
    __shared__ float cs[64][2];

    const int r  = tid >> 2, seg  = tid & 3;     // A: 64 rows x 16 f32
    const int r2 = tid >> 1, seg2 = tid & 1;     // B: 128 rows x 32 bf16
    const float*          gA = tokens + (size_t)(t0 + r)*D_ + seg*16;
    const unsigned short* gB = cn     + (size_t)r2*D_       + seg2*32;
    unsigned short* sA = lds_a + r*72  + seg*16;
    unsigned short* sB = lds_b + r2*72 + seg2*32;

    const int lane = tid & 63, w = tid >> 6;
    const int wm = w >> 1, wn = w & 1, lrow = lane & 15, quad = lane >> 4;

    f32x4 acc[2][4];
    #pragma unroll
    for (int i = 0; i < 2; i++)
        #pragma unroll
        for (int j = 0; j < 4; j++) acc[i][j] = (f32x4){0.f,0.f,0.f,0.f};

    float ss = 0.f;

    for (int ki = 0; ki < 16; ki++){
        const int k0 = ki * 64;
        #pragma unroll
        for (int j = 0; j < 4; j++){
            float4 ra = *(const float4*)(gA + k0 + j*4);
            ss += ra.x*ra.x + ra.y*ra.y + ra.z*ra.z + ra.w*ra.w;
            unsigned int lo = (unsigned int)f2b(ra.x) | ((unsigned int)f2b(ra.y) << 16);
            unsigned int hi = (unsigned int)f2b(ra.z) | ((unsigned int)f2b(ra.w) << 16);
            *(uint2*)(sA + j*4) = make_uint2(lo, hi);
        }
        #pragma unroll
        for (int j = 0; j < 4; j++)
            *(uint4*)(sB + j*8) = *(const uint4*)(gB + k0 + j*8);
        __syncthreads();
        #pragma unroll
        for (int kk = 0; kk < 64; kk += 32){
            bf16x8 af[2], bfr[4];
            #pragma unroll
            for (int mi = 0; mi < 2; mi++)
                af[mi] = *(const bf16x8*)(lds_a + (wm*32 + mi*16 + lrow)*72 + kk + quad*8);
            #pragma unroll
            for (int ni = 0; ni < 4; ni++)
                bfr[ni] = *(const bf16x8*)(lds_b + (wn*64 + ni*16 + lrow)*72 + kk + quad*8);
            #pragma unroll
            for (int mi = 0; mi < 2; mi++)
                #pragma unroll
                for (int ni = 0; ni < 4; ni++)
                    acc[mi][ni] = __builtin_amdgcn_mfma_f32_16x16x32_bf16(af[mi], bfr[ni], acc[mi][ni], 0, 0, 0);
        }
        __syncthreads();
    }

    // token norms: 4 partials per row
    red[tid] = ss; __syncthreads();
    if (tid < 64){
        float tot = red[4*tid] + red[4*tid+1] + red[4*tid+2] + red[4*tid+3];
        srow[tid] = 10.0f / fmaxf(sqrtf(tot), 1e-12f);  // 1/(max(||x||,eps)*TEMP)
    }
    __syncthreads();

    // scale in-place; per-row max+sum (registers + quad shuffles)
    float rm[2][4], rs[2][4];
    #pragma unroll
    for (int mi = 0; mi < 2; mi++){
        #pragma unroll
        for (int rr = 0; rr < 4; rr++){
            int row = wm*32 + mi*16 + quad*4 + rr;
            float sc = srow[row];
            float m = -1e30f;
            #pragma unroll
            for (int ni = 0; ni < 4; ni++){
                int col = wn*64 + ni*16 + lrow;
                float v = acc[mi][ni][rr] * sc;
                acc[mi][ni][rr] = v;
                if (col < E_) m = fmaxf(m, v);
            }
            #pragma unroll
            for (int off = 1; off < 16; off <<= 1)
                m = fmaxf(m, __shfl_xor(m, off));
            float s = 0.f;
            #pragma unroll
            for (int ni = 0; ni < 4; ni++){
                int col = wn*64 + ni*16 + lrow;
                s += (col < E_) ? __expf(acc[mi][ni][rr] - m) : 0.f;
            }
            #pragma unroll
            for (int off = 1; off < 16; off <<= 1)
                s += __shfl_xor(s, off);
            rm[mi][rr] = m; rs[mi][rr] = s;
        }
    }
    if (lrow == 0){
        #pragma unroll
        for (int mi = 0; mi < 2; mi++)
            #pragma unroll
            for (int rr = 0; rr < 4; rr++){
                int row = wm*32 + mi*16 + quad*4 + rr;
                cm[row][wn] = rm[mi][rr];
                cs[row][wn] = rs[mi][rr];
            }
    }
    __syncthreads();

    // final p; fp32 out_assign; bf16 -> LDS transpose tile spT[e][t] (reuses lds_b)
    unsigned short* spT = lds_b;   // [128][72] shorts
    #pragma unroll
    for (int mi = 0; mi < 2; mi++){
        #pragma unroll
        for (int rr = 0; rr < 4; rr++){
            int row = wm*32 + mi*16 + quad*4 + rr;
            float m0 = cm[row][0], m1 = cm[row][1];
            float M  = fmaxf(m0, m1);
            float S  = cs[row][0]*__expf(m0 - M) + cs[row][1]*__expf(m1 - M);
            float rinv = 1.0f / S;
            #pragma unroll
            for (int ni = 0; ni < 4; ni++){
                int col = wn*64 + ni*16 + lrow;
                float p = 0.f;
                if (col < E_){
                    p = __expf(acc[mi][ni][rr] - M) * rinv;
                    out_assign[(size_t)(t0 + row)*E_ + col] = p;
                }
                spT[col*72 + row] = f2b(p);   // zeros for padded e-rows
            }
        }
    }
    __syncthreads();

    // coalesced pT store: 128 e-rows x 64 t (16 KB), 4 dwordx4 per thread
    #pragma unroll
    for (int c = 0; c < 4; c++){
        int i = tid*4 + c;          // 0..1023
        int e = i >> 3;             // 0..127
        int o = (i & 7) * 8;        // t-offset in shorts
        uint4 v = *(const uint4*)(spT + e*72 + o);
        *(uint4*)(pT + ((size_t)bb*EP_ + e)*T_ + tl0 + o) = v;
    }
}

// ---------------- K3: partial entity_features (no atomics) ---------------------
// grid = (32 d-tiles, TC_ t-chunks, 8 batches), 256 threads. Tile 128e x 32d.
__global__ __launch_bounds__(256) void k_feat(const float* __restrict__ tokens,
                                              const unsigned short* __restrict__ pT,
                                              float* __restrict__ facc_part){
    const int tid = threadIdx.x;
    const int d0  = blockIdx.x * 32;
    const int tc  = blockIdx.y;
    const int bb  = blockIdx.z;
    const int KT  = T_ / TC_;       // 2048

    __shared__ __align__(16) unsigned short lds_a[128*72];   // [e][t] bf16
    __shared__ __align__(16) unsigned short lds_bt[32*72];   // [d][t] bf16

    const int r = tid >> 1, seg = tid & 1;
    const unsigned short* gA = pT + ((size_t)bb*EP_ + r)*T_ + tc*KT + seg*32;
    unsigned short* sA = lds_a + r*72 + seg*32;

    const int tr = tid >> 2, dseg = tid & 3;
    const float* gB = tokens + ((size_t)(bb*T_ + tc*KT + tr))*D_ + d0 + dseg*8;

    const int lane = tid & 63, w = tid >> 6, lrow = lane & 15, quad = lane >> 4;

    f32x4 acc[2][2];
    #pragma unroll
    for (int i = 0; i < 2; i++)
        #pragma unroll
        for (int j = 0; j < 2; j++) acc[i][j] = (f32x4){0.f,0.f,0.f,0.f};

    for (int kt0 = 0; kt0 < KT; kt0 += 64){
        #pragma unroll
        for (int j = 0; j < 4; j++)
            *(uint4*)(sA + j*8) = *(const uint4*)(gA + kt0 + j*8);
        #pragma unroll
        for (int j = 0; j < 2; j++){
            float4 rb = *(const float4*)(gB + (size_t)kt0*D_ + j*4);
            int dloc = dseg*8 + j*4;
            lds_bt[(dloc+0)*72 + tr] = f2b(rb.x);
            lds_bt[(dloc+1)*72 + tr] = f2b(rb.y);
            lds_bt[(dloc+2)*72 + tr] = f2b(rb.z);
            lds_bt[(dloc+3)*72 + tr] = f2b(rb.w);
        }
        __syncthreads();
        #pragma unroll
        for (int kk = 0; kk < 64; kk += 32){
            bf16x8 af[2], bfr[2];
            #pragma unroll
            for (int mi = 0; mi < 2; mi++)
                af[mi] = *(const bf16x8*)(lds_a + (w*32 + mi*16 + lrow)*72 + kk + quad*8);
            #pragma unroll
            for (int ni = 0; ni < 2; ni++)
                bfr[ni] = *(const bf16x8*)(lds_bt + (ni*16 + lrow)*72 + kk + quad*8);
            #pragma unroll
            for (int mi = 0; mi < 2; mi++)
                #pragma unroll
                for (int ni = 0; ni < 2; ni++)
                    acc[mi][ni] = __builtin_amdgcn_mfma_f32_16x16x32_bf16(af[mi], bfr[ni], acc[mi][ni], 0, 0, 0);
        }
        __syncthreads();
    }

    #pragma unroll
    for (int mi = 0; mi < 2; mi++){
        #pragma unroll
        for (int ni = 0; ni < 2; ni++){
            int d = d0 + ni*16 + lrow;
            #pragma unroll
            for (int rr = 0; rr < 4; rr++){
                int e = w*32 + mi*16 + quad*4 + rr;
                if (e < E_)
                    facc_part[((size_t)(tc*B_ + bb)*E_ + e)*D_ + d] = acc[mi][ni][rr];
            }
        }
    }
}

// ---------------- K4: w = sum_t pT; out = (part0+part1)/(w+eps) ----------------
// grid = (E_, B_), 256 threads.
__global__ __launch_bounds__(256) void k_final(const unsigned short* __restrict__ pT,
                                               const float* __restrict__ facc_part,
                                               float* __restrict__ out_feat){
    const int e  = blockIdx.x;
    const int bb = blockIdx.y;
    const int tid = threadIdx.x;

    __shared__ float red[256];
    const unsigned short* prow = pT + ((size_t)bb*EP_ + e)*T_;
    float s = 0.f;
    #pragma unroll
    for (int j = 0; j < 2; j++){
        uint4 v = *(const uint4*)(prow + tid*16 + j*8);
        s += b2f(v.x & 0xffffu) + b2f(v.x >> 16)
           + b2f(v.y & 0xffffu) + b2f(v.y >> 16)
           + b2f(v.z & 0xffffu) + b2f(v.z >> 16)
           + b2f(v.w & 0xffffu) + b2f(v.w >> 16);
    }
    red[tid] = s; __syncthreads();
    for (int st = 128; st > 0; st >>= 1){ if (tid < st) red[tid] += red[tid+st]; __syncthreads(); }
    float winv = 1.0f / (red[0] + 1e-6f);

    const int d = tid * 4;
    float4 p0 = *(const float4*)(facc_part + ((size_t)(0*B_ + bb)*E_ + e)*D_ + d);
    float4 p1 = *(const float4*)(facc_part + ((size_t)(1*B_ + bb)*E_ + e)*D_ + d);
    float4 o;
    o.x = (p0.x + p1.x) * winv;
    o.y = (p0.y + p1.y) * winv;
    o.z = (p0.z + p1.z) * winv;
    o.w = (p0.w + p1.w) * winv;
    *(float4*)(out_feat + ((size_t)bb*E_ + e)*D_ + d) = o;
}

extern "C" void kernel_launch(void* const* d_in, const int* in_sizes, int n_in,
                              void* d_out, int out_size, void* d_ws, size_t ws_size,
                              hipStream_t stream){
    const float* tokens = (const float*)d_in[0];
    const float* cent   = (const float*)d_in[1];
    float* out        = (float*)d_out;
    float* out_assign = out;
    float* out_feat   = out + (size_t)B_*T_*E_;

    float* facc_part = (float*)d_ws;                               // TC_*B*E*D fp32 (6.55 MB)
    unsigned short* cn = (unsigned short*)(facc_part + (size_t)TC_*B_*E_*D_);  // EP_*D_ bf16
    unsigned short* pT = cn + (size_t)EP_*D_;                      // B_*EP_*T_ bf16 (8 MB)

    k_cnorm<<<EP_, 256, 0, stream>>>(cent, cn);
    k_sim<<<NTOK/64, 256, 0, stream>>>(tokens, cn, out_assign, pT);
    k_feat<<<dim3(32, TC_, B_), 256, 0, stream>>>(tokens, pT, facc_part);
    k_final<<<dim3(E_, B_), 256, 0, stream>>>(pT, facc_part, out_feat);
}

// Round 5
// 262.521 us; speedup vs baseline: 1.0241x; 1.0241x over previous
//
#include <hip/hip_runtime.h>

#define B_   8
#define T_   4096
#define D_   1024
#define E_   100
#define EP_  128
#define NTOK (B_*T_)
#define TC_  4            // t-chunks in k_feat

typedef short bf16x8 __attribute__((ext_vector_type(8)));
typedef float f32x4  __attribute__((ext_vector_type(4)));

__device__ __forceinline__ float b2f(unsigned int u){
    union { unsigned int i; float f; } v; v.i = u << 16; return v.f;
}
__device__ __forceinline__ unsigned short f2b(float f){
    union { float f; unsigned int i; } v; v.f = f;
    unsigned int x = v.i;
    return (unsigned short)((x + 0x7fffu + ((x >> 16) & 1u)) >> 16);
}

// ---------------- K1: normalize centroids (fp32 in) -> cn[EP_][D_] bf16 --------
__global__ __launch_bounds__(256) void k_cnorm(const float* __restrict__ cent,
                                               unsigned short* __restrict__ cn){
    const int e = blockIdx.x, tid = threadIdx.x;
    if (e >= E_){
        ((uint2*)(cn + (size_t)e*D_))[tid] = make_uint2(0u, 0u);
        return;
    }
    float4 x = ((const float4*)(cent + (size_t)e*D_))[tid];
    float ss = x.x*x.x + x.y*x.y + x.z*x.z + x.w*x.w;
    __shared__ float red[256];
    red[tid] = ss; __syncthreads();
    for (int s = 128; s > 0; s >>= 1){ if (tid < s) red[tid] += red[tid+s]; __syncthreads(); }
    float inv = 1.0f / fmaxf(sqrtf(red[0]), 1e-12f);
    unsigned int lo = (unsigned int)f2b(x.x*inv) | ((unsigned int)f2b(x.y*inv) << 16);
    unsigned int hi = (unsigned int)f2b(x.z*inv) | ((unsigned int)f2b(x.w*inv) << 16);
    ((uint2*)(cn + (size_t)e*D_))[tid] = make_uint2(lo, hi);
}

// ---------------- K2: sim GEMM + register softmax ------------------------------
// grid = NTOK/32 = 1024 blocks (4/CU), 256 threads. Tile: 32 tokens x 128 entities.
// Dense staging: every global load instruction touches fully-used cache lines.
__global__ __launch_bounds__(256) void k_sim(const float* __restrict__ tokens,
                                             const unsigned short* __restrict__ cn,
                                             float* __restrict__ out_assign,
                                             unsigned short* __restrict__ pT){
    const int tid = threadIdx.x;
    const int t0  = blockIdx.x * 32;
    const int bb  = t0 >> 12;
    const int tl0 = t0 & (T_ - 1);

    __shared__ __align__(16) unsigned short lds_a[32*72];     // [t][k] bf16
    __shared__ __align__(16) unsigned short lds_b[128*72];    // [e][k] bf16; later spT [128][40]
    __shared__ float red[32][16];
    __shared__ float srow[32];
    __shared__ float cm[32][2];
    __shared__ float cs[32][2];

    // A: 32 rows x 64 f32 per iter. lane map: i=tid+256j (j=0,1), row=i>>4, off=(i&15)*4 floats
    const float* gA[2]; unsigned short* sA[2];
    #pragma unroll
    for (int j = 0; j < 2; j++){
        int row = (tid >> 4) + 16*j;
        gA[j] = tokens + (size_t)(t0 + row)*D_ + (tid & 15)*4;
        sA[j] = lds_a + row*72 + (tid & 15)*4;
    }
    // B: 128 rows x 64 bf16 per iter. lane map: i=tid+256j (j=0..3), row=i>>3, off=(tid&7)*8 shorts
    const unsigned short* gB[4]; unsigned short* sB[4];
    #pragma unroll
    for (int j = 0; j < 4; j++){
        int row = (tid >> 3) + 32*j;
        gB[j] = cn + (size_t)row*D_ + (tid & 7)*8;
        sB[j] = lds_b + row*72 + (tid & 7)*8;
    }

    const int lane = tid & 63, w = tid >> 6;
    const int wm = w >> 1, wn = w & 1, lrow = lane & 15, quad = lane >> 4;

    f32x4 acc[4];
    #pragma unroll
    for (int j = 0; j < 4; j++) acc[j] = (f32x4){0.f,0.f,0.f,0.f};

    float ss[2] = {0.f, 0.f};

    for (int ki = 0; ki < 16; ki++){
        const int k0 = ki * 64;
        #pragma unroll
        for (int j = 0; j < 2; j++){
            float4 ra = *(const float4*)(gA[j] + k0);
            ss[j] += ra.x*ra.x + ra.y*ra.y + ra.z*ra.z + ra.w*ra.w;
            unsigned int lo = (unsigned int)f2b(ra.x) | ((unsigned int)f2b(ra.y) << 16);
            unsigned int hi = (unsigned int)f2b(ra.z) | ((unsigned int)f2b(ra.w) << 16);
            *(uint2*)(sA[j]) = make_uint2(lo, hi);
        }
        #pragma unroll
        for (int j = 0; j < 4; j++)
            *(uint4*)(sB[j]) = *(const uint4*)(gB[j] + k0);
        __syncthreads();
        #pragma unroll
        for (int kk = 0; kk < 64; kk += 32){
            bf16x8 af, bfr[4];
            af = *(const bf16x8*)(lds_a + (wm*16 + lrow)*72 + kk + quad*8);
            #pragma unroll
            for (int ni = 0; ni < 4; ni++)
                bfr[ni] = *(const bf16x8*)(lds_b + (wn*64 + ni*16 + lrow)*72 + kk + quad*8);
            #pragma unroll
            for (int ni = 0; ni < 4; ni++)
                acc[ni] = __builtin_amdgcn_mfma_f32_16x16x32_bf16(af, bfr[ni], acc[ni], 0, 0, 0);
        }
        __syncthreads();
    }

    // token norms
    red[(tid >> 4)     ][tid & 15] = ss[0];
    red[(tid >> 4) + 16][tid & 15] = ss[1];
    __syncthreads();
    if (tid < 32){
        float tot = 0.f;
        #pragma unroll
        for (int c = 0; c < 16; c++) tot += red[tid][c];
        srow[tid] = 10.0f / fmaxf(sqrtf(tot), 1e-12f);   // 1/(max(||x||,eps)*TEMP)
    }
    __syncthreads();

    // softmax in registers (rows: wm*16 + quad*4 + rr)
    float rm[4], rs[4];
    #pragma unroll
    for (int rr = 0; rr < 4; rr++){
        int row = wm*16 + quad*4 + rr;
        float sc = srow[row];
        float m = -1e30f;
        #pragma unroll
        for (int ni = 0; ni < 4; ni++){
            int col = wn*64 + ni*16 + lrow;
            float v = acc[ni][rr] * sc;
            acc[ni][rr] = v;
            if (col < E_) m = fmaxf(m, v);
        }
        #pragma unroll
        for (int off = 1; off < 16; off <<= 1)
            m = fmaxf(m, __shfl_xor(m, off));
        float s = 0.f;
        #pragma unroll
        for (int ni = 0; ni < 4; ni++){
            int col = wn*64 + ni*16 + lrow;
            s += (col < E_) ? __expf(acc[ni][rr] - m) : 0.f;
        }
        #pragma unroll
        for (int off = 1; off < 16; off <<= 1)
            s += __shfl_xor(s, off);
        rm[rr] = m; rs[rr] = s;
    }
    if (lrow == 0){
        #pragma unroll
        for (int rr = 0; rr < 4; rr++){
            int row = wm*16 + quad*4 + rr;
            cm[row][wn] = rm[rr];
            cs[row][wn] = rs[rr];
        }
    }
    __syncthreads();

    // final p; fp32 out_assign; bf16 transpose tile spT[e][t] (stride 40, reuses lds_b)
    unsigned short* spT = lds_b;
    #pragma unroll
    for (int rr = 0; rr < 4; rr++){
        int row = wm*16 + quad*4 + rr;
        float m0 = cm[row][0], m1 = cm[row][1];
        float M  = fmaxf(m0, m1);
        float S  = cs[row][0]*__expf(m0 - M) + cs[row][1]*__expf(m1 - M);
        float rinv = 1.0f / S;
        #pragma unroll
        for (int ni = 0; ni < 4; ni++){
            int col = wn*64 + ni*16 + lrow;
            float p = 0.f;
            if (col < E_){
                p = __expf(acc[ni][rr] - M) * rinv;
                out_assign[(size_t)(t0 + row)*E_ + col] = p;
            }
            spT[col*40 + row] = f2b(p);
        }
    }
    __syncthreads();

    // coalesced pT store: 128 e-rows x 32 t (8 KB)
    #pragma unroll
    for (int j = 0; j < 2; j++){
        int i = tid + 256*j;
        int e = i >> 2;             // 0..127
        int o = (i & 3) * 8;        // t-offset in shorts (16B chunks)
        uint4 v = *(const uint4*)(spT + e*40 + o);
        *(uint4*)(pT + ((size_t)bb*EP_ + e)*T_ + tl0 + o) = v;
    }
}

// ---------------- K3: partial entity_features (no atomics, dense loads) --------
// grid = (16 d-tiles, TC_ t-chunks, 8 batches) = 512 blocks. Tile 128e x 64d, K=1024.
__global__ __launch_bounds__(256) void k_feat(const float* __restrict__ tokens,
                                              const unsigned short* __restrict__ pT,
                                              float* __restrict__ facc_part){
    const int tid = threadIdx.x;
    const int d0  = blockIdx.x * 64;
    const int tc  = blockIdx.y;
    const int bb  = blockIdx.z;
    const int KT  = T_ / TC_;       // 1024

    __shared__ __align__(16) unsigned short lds_a[128*72];   // [e][t] bf16
    __shared__ __align__(16) unsigned short lds_bt[64*72];   // [d][t] bf16 (transposed x)

    // A (pT): 128 rows x 64 shorts per iter. i=tid+256j (j=0..3), row=i>>3, off=(tid&7)*8
    const unsigned short* gA[4]; unsigned short* sA[4];
    #pragma unroll
    for (int j = 0; j < 4; j++){
        int row = (tid >> 3) + 32*j;
        gA[j] = pT + ((size_t)bb*EP_ + row)*T_ + tc*KT + (tid & 7)*8;
        sA[j] = lds_a + row*72 + (tid & 7)*8;
    }
    // B (tokens fp32): 64 t-rows x 64 d per iter. i=tid+256j (j=0..3), trow=i>>4, doff=(tid&15)*4
    const float* gB[4];
    #pragma unroll
    for (int j = 0; j < 4; j++){
        int trow = (tid >> 4) + 16*j;
        gB[j] = tokens + ((size_t)(bb*T_ + tc*KT + trow))*D_ + d0 + (tid & 15)*4;
    }

    const int lane = tid & 63, w = tid >> 6;
    const int wm = w >> 1, wn = w & 1, lrow = lane & 15, quad = lane >> 4;

    f32x4 acc[4][2];
    #pragma unroll
    for (int i = 0; i < 4; i++)
        #pragma unroll
        for (int j = 0; j < 2; j++) acc[i][j] = (f32x4){0.f,0.f,0.f,0.f};

    for (int kt0 = 0; kt0 < KT; kt0 += 64){
        #pragma unroll
        for (int j = 0; j < 4; j++)
            *(uint4*)(sA[j]) = *(const uint4*)(gA[j] + kt0);
        #pragma unroll
        for (int j = 0; j < 4; j++){
            float4 rb = *(const float4*)(gB[j] + (size_t)kt0*D_);
            int trow = (tid >> 4) + 16*j;
            int dloc = (tid & 15)*4;
            lds_bt[(dloc+0)*72 + trow] = f2b(rb.x);
            lds_bt[(dloc+1)*72 + trow] = f2b(rb.y);
            lds_bt[(dloc+2)*72 + trow] = f2b(rb.z);
            lds_bt[(dloc+3)*72 + trow] = f2b(rb.w);
        }
        __syncthreads();
        #pragma unroll
        for (int kk = 0; kk < 64; kk += 32){
            bf16x8 af[4], bfr[2];
            #pragma unroll
            for (int mi = 0; mi < 4; mi++)
                af[mi] = *(const bf16x8*)(lds_a + (wm*64 + mi*16 + lrow)*72 + kk + quad*8);
            #pragma unroll
            for (int ni = 0; ni < 2; ni++)
                bfr[ni] = *(const bf16x8*)(lds_bt + (wn*32 + ni*16 + lrow)*72 + kk + quad*8);
            #pragma unroll
            for (int mi = 0; mi < 4; mi++)
                #pragma unroll
                for (int ni = 0; ni < 2; ni++)
                    acc[mi][ni] = __builtin_amdgcn_mfma_f32_16x16x32_bf16(af[mi], bfr[ni], acc[mi][ni], 0, 0, 0);
        }
        __syncthreads();
    }

    #pragma unroll
    for (int mi = 0; mi < 4; mi++){
        #pragma unroll
        for (int ni = 0; ni < 2; ni++){
            int d = d0 + wn*32 + ni*16 + lrow;
            #pragma unroll
            for (int rr = 0; rr < 4; rr++){
                int e = wm*64 + mi*16 + quad*4 + rr;
                if (e < E_)
                    facc_part[((size_t)(tc*B_ + bb)*E_ + e)*D_ + d] = acc[mi][ni][rr];
            }
        }
    }
}

// ---------------- K4: w = sum_t pT; out = (sum parts)/(w+eps) ------------------
// grid = (E_, B_), 256 threads.
__global__ __launch_bounds__(256) void k_final(const unsigned short* __restrict__ pT,
                                               const float* __restrict__ facc_part,
                                               float* __restrict__ out_feat){
    const int e  = blockIdx.x;
    const int bb = blockIdx.y;
    const int tid = threadIdx.x;

    __shared__ float red[256];
    const unsigned short* prow = pT + ((size_t)bb*EP_ + e)*T_;
    float s = 0.f;
    #pragma unroll
    for (int j = 0; j < 2; j++){
        uint4 v = *(const uint4*)(prow + tid*16 + j*8);
        s += b2f(v.x & 0xffffu) + b2f(v.x >> 16)
           + b2f(v.y & 0xffffu) + b2f(v.y >> 16)
           + b2f(v.z & 0xffffu) + b2f(v.z >> 16)
           + b2f(v.w & 0xffffu) + b2f(v.w >> 16);
    }
    red[tid] = s; __syncthreads();
    for (int st = 128; st > 0; st >>= 1){ if (tid < st) red[tid] += red[tid+st]; __syncthreads(); }
    float winv = 1.0f / (red[0] + 1e-6f);

    const int d = tid * 4;
    float4 o = make_float4(0.f, 0.f, 0.f, 0.f);
    #pragma unroll
    for (int tc = 0; tc < TC_; tc++){
        float4 p = *(const float4*)(facc_part + ((size_t)(tc*B_ + bb)*E_ + e)*D_ + d);
        o.x += p.x; o.y += p.y; o.z += p.z; o.w += p.w;
    }
    o.x *= winv; o.y *= winv; o.z *= winv; o.w *= winv;
    *(float4*)(out_feat + ((size_t)bb*E_ + e)*D_ + d) = o;
}

extern "C" void kernel_launch(void* const* d_in, const int* in_sizes, int n_in,
                              void* d_out, int out_size, void* d_ws, size_t ws_size,
                              hipStream_t stream){
    const float* tokens = (const float*)d_in[0];
    const float* cent   = (const float*)d_in[1];
    float* out        = (float*)d_out;
    float* out_assign = out;
    float* out_feat   = out + (size_t)B_*T_*E_;

    float* facc_part = (float*)d_ws;                                           // TC_*B*E*D fp32 (13.1 MB)
    unsigned short* cn = (unsigned short*)(facc_part + (size_t)TC_*B_*E_*D_);  // EP_*D_ bf16
    unsigned short* pT = cn + (size_t)EP_*D_;                                  // B_*EP_*T_ bf16 (8 MB)

    k_cnorm<<<EP_, 256, 0, stream>>>(cent, cn);
    k_sim<<<NTOK/32, 256, 0, stream>>>(tokens, cn, out_assign, pT);
    k_feat<<<dim3(16, TC_, B_), 256, 0, stream>>>(tokens, pT, facc_part);
    k_final<<<dim3(E_, B_), 256, 0, stream>>>(pT, facc_part, out_feat);
}

// Round 6
// 254.153 us; speedup vs baseline: 1.0578x; 1.0329x over previous
//
#include <hip/hip_runtime.h>

#define B_   8
#define T_   4096
#define D_   1024
#define E_   100
#define EP_  128
#define NTOK (B_*T_)
#define TC_  4            // t-chunks in k_feat

typedef short bf16x8 __attribute__((ext_vector_type(8)));
typedef float f32x4  __attribute__((ext_vector_type(4)));

__device__ __forceinline__ float b2f(unsigned int u){
    union { unsigned int i; float f; } v; v.i = u << 16; return v.f;
}
__device__ __forceinline__ unsigned short f2b(float f){
    union { float f; unsigned int i; } v; v.f = f;
    unsigned int x = v.i;
    return (unsigned short)((x + 0x7fffu + ((x >> 16) & 1u)) >> 16);
}
__device__ __forceinline__ void dma16(const unsigned short* g, unsigned short* l){
    __builtin_amdgcn_global_load_lds(
        (const __attribute__((address_space(1))) unsigned int*)(const void*)g,
        (__attribute__((address_space(3))) unsigned int*)(void*)l,
        16, 0, 0);
}

// ---------------- K0: tokens fp32 -> tb bf16 + norms (streaming probe) ---------
// grid = NTOK/4 blocks, 256 threads (1 wave per token row).
__global__ __launch_bounds__(256) void k_prep(const float* __restrict__ tokens,
                                              unsigned short* __restrict__ tb,
                                              float* __restrict__ norms){
    const int row  = blockIdx.x*4 + (threadIdx.x >> 6);
    const int lane = threadIdx.x & 63;
    const float* src = tokens + (size_t)row*D_;
    unsigned short* dst = tb + (size_t)row*D_;
    float4 v[4];
    float ss = 0.f;
    #pragma unroll
    for (int j = 0; j < 4; j++){
        v[j] = *(const float4*)(src + lane*4 + j*256);
        ss += v[j].x*v[j].x + v[j].y*v[j].y + v[j].z*v[j].z + v[j].w*v[j].w;
    }
    #pragma unroll
    for (int off = 1; off < 64; off <<= 1) ss += __shfl_xor(ss, off);
    if (lane == 0) norms[row] = 10.0f / fmaxf(sqrtf(ss), 1e-12f);  // 1/(max(||x||,eps)*TEMP)
    #pragma unroll
    for (int j = 0; j < 4; j++){
        unsigned int lo = (unsigned int)f2b(v[j].x) | ((unsigned int)f2b(v[j].y) << 16);
        unsigned int hi = (unsigned int)f2b(v[j].z) | ((unsigned int)f2b(v[j].w) << 16);
        *(uint2*)(dst + lane*4 + j*256) = make_uint2(lo, hi);
    }
}

// ---------------- K1: normalize centroids (fp32 in) -> cn[EP_][D_] bf16 --------
__global__ __launch_bounds__(256) void k_cnorm(const float* __restrict__ cent,
                                               unsigned short* __restrict__ cn){
    const int e = blockIdx.x, tid = threadIdx.x;
    if (e >= E_){
        ((uint2*)(cn + (size_t)e*D_))[tid] = make_uint2(0u, 0u);
        return;
    }
    float4 x = ((const float4*)(cent + (size_t)e*D_))[tid];
    float ss = x.x*x.x + x.y*x.y + x.z*x.z + x.w*x.w;
    __shared__ float red[256];
    red[tid] = ss; __syncthreads();
    for (int s = 128; s > 0; s >>= 1){ if (tid < s) red[tid] += red[tid+s]; __syncthreads(); }
    float inv = 1.0f / fmaxf(sqrtf(red[0]), 1e-12f);
    unsigned int lo = (unsigned int)f2b(x.x*inv) | ((unsigned int)f2b(x.y*inv) << 16);
    unsigned int hi = (unsigned int)f2b(x.z*inv) | ((unsigned int)f2b(x.w*inv) << 16);
    ((uint2*)(cn + (size_t)e*D_))[tid] = make_uint2(lo, hi);
}

// ---------------- K2: sim GEMM (DMA dbuf staging) + register softmax -----------
// grid = NTOK/32 = 1024 blocks (4/CU @ 40KB LDS), 256 threads. Tile 32t x 128e.
__global__ __launch_bounds__(256) void k_sim(const unsigned short* __restrict__ tb,
                                             const unsigned short* __restrict__ cn,
                                             const float* __restrict__ norms,
                                             float* __restrict__ out_assign,
                                             unsigned short* __restrict__ pT,
                                             float* __restrict__ wpart){
    __shared__ __align__(16) char smem[40960];
    unsigned short* aBuf[2] = {(unsigned short*)smem, (unsigned short*)(smem + 4096)};
    unsigned short* bBuf[2] = {(unsigned short*)(smem + 8192), (unsigned short*)(smem + 8192 + 16384)};

    const int tid = threadIdx.x;
    const int t0  = blockIdx.x * 32;
    const int bb  = t0 >> 12;
    const int tl0 = t0 & (T_ - 1);
    const int lane = tid & 63, w = tid >> 6;
    const int wm = w >> 1, wn = w & 1, lrow = lane & 15, quad = lane >> 4;

    // A DMA: wave w fills rows 8w..8w+7 (1 KB chunk). lane l -> row 8w+(l>>3),
    // fetches global k-block (l&7)^(row&7) so LDS slot s holds block s^(row&7).
    const int arow = 8*w + (lane >> 3);
    const int ajg  = (lane & 7) ^ (arow & 7);
    const unsigned short* gA = tb + (size_t)(t0 + arow)*D_ + ajg*8;
    unsigned short* lA[2] = { aBuf[0] + w*512, aBuf[1] + w*512 };

    // B DMA: wave w fills chunks c=4w..4w+3 (rows 8c..8c+7 each).
    const unsigned short* gB[4];
    unsigned short* lB[2][4];
    #pragma unroll
    for (int j = 0; j < 4; j++){
        int c = 4*w + j;
        int brow = 8*c + (lane >> 3);
        int bjg  = (lane & 7) ^ (brow & 7);
        gB[j] = cn + (size_t)brow*D_ + bjg*8;
        lB[0][j] = bBuf[0] + c*512;
        lB[1][j] = bBuf[1] + c*512;
    }

    f32x4 acc[4];
    #pragma unroll
    for (int j = 0; j < 4; j++) acc[j] = (f32x4){0.f,0.f,0.f,0.f};

    // prologue: buffer 0, k0 = 0
    dma16(gA, lA[0]);
    #pragma unroll
    for (int j = 0; j < 4; j++) dma16(gB[j], lB[0][j]);

    for (int ki = 0; ki < 16; ki++){
        const int cur = ki & 1;
        __syncthreads();                      // drains cur-buffer DMAs (vmcnt(0)+barrier)
        if (ki < 15){
            const int k0 = (ki + 1) * 64;
            dma16(gA + k0, lA[1 - cur]);      // next-tile loads fly during MFMA below
            #pragma unroll
            for (int j = 0; j < 4; j++) dma16(gB[j] + k0, lB[1 - cur][j]);
        }
        const unsigned short* aC = aBuf[cur];
        const unsigned short* bC = bBuf[cur];
        #pragma unroll
        for (int kk = 0; kk < 2; kk++){
            const int b = quad + 4*kk;
            const int m = wm*16 + lrow;
            bf16x8 af = *(const bf16x8*)(aC + m*64 + ((b ^ (m & 7)) * 8));
            #pragma unroll
            for (int ni = 0; ni < 4; ni++){
                const int n = wn*64 + ni*16 + lrow;
                bf16x8 bfr = *(const bf16x8*)(bC + n*64 + ((b ^ (n & 7)) * 8));
                acc[ni] = __builtin_amdgcn_mfma_f32_16x16x32_bf16(af, bfr, acc[ni], 0, 0, 0);
            }
        }
    }
    __syncthreads();   // all MFMA reads done; smem reusable

    // overlays
    float* cmA  = (float*)smem;               // [32][2]
    float* csA  = (float*)(smem + 256);       // [32][2]
    float* wsum = (float*)(smem + 512);       // [128]
    unsigned short* spT = (unsigned short*)(smem + 8192);  // [128][40]

    if (tid < 128) wsum[tid] = 0.f;

    // scale by norms, row max+sum via 16-lane shuffles
    float rm[4], rs[4];
    #pragma unroll
    for (int rr = 0; rr < 4; rr++){
        const int row = wm*16 + quad*4 + rr;
        const float sc = norms[t0 + row];
        float m = -1e30f;
        #pragma unroll
        for (int ni = 0; ni < 4; ni++){
            const int col = wn*64 + ni*16 + lrow;
            float v = acc[ni][rr] * sc;
            acc[ni][rr] = v;
            if (col < E_) m = fmaxf(m, v);
        }
        #pragma unroll
        for (int off = 1; off < 16; off <<= 1) m = fmaxf(m, __shfl_xor(m, off));
        float s = 0.f;
        #pragma unroll
        for (int ni = 0; ni < 4; ni++){
            const int col = wn*64 + ni*16 + lrow;
            s += (col < E_) ? __expf(acc[ni][rr] - m) : 0.f;
        }
        #pragma unroll
        for (int off = 1; off < 16; off <<= 1) s += __shfl_xor(s, off);
        rm[rr] = m; rs[rr] = s;
    }
    if (lrow == 0){
        #pragma unroll
        for (int rr = 0; rr < 4; rr++){
            const int row = wm*16 + quad*4 + rr;
            cmA[row*2 + wn] = rm[rr];
            csA[row*2 + wn] = rs[rr];
        }
    }
    __syncthreads();

    // final p; fp32 out_assign; bf16 transpose tile; weight partials
    float wp[4] = {0.f, 0.f, 0.f, 0.f};
    #pragma unroll
    for (int rr = 0; rr < 4; rr++){
        const int row = wm*16 + quad*4 + rr;
        const float m0 = cmA[row*2], m1 = cmA[row*2 + 1];
        const float M  = fmaxf(m0, m1);
        const float S  = csA[row*2]*__expf(m0 - M) + csA[row*2 + 1]*__expf(m1 - M);
        const float rinv = 1.0f / S;
        #pragma unroll
        for (int ni = 0; ni < 4; ni++){
            const int col = wn*64 + ni*16 + lrow;
            float p = 0.f;
            if (col < E_){
                p = __expf(acc[ni][rr] - M) * rinv;
                out_assign[(size_t)(t0 + row)*E_ + col] = p;
                wp[ni] += p;
            }
            spT[col*40 + row] = f2b(p);
        }
    }
    #pragma unroll
    for (int ni = 0; ni < 4; ni++){
        const int col = wn*64 + ni*16 + lrow;
        float v = wp[ni];
        v += __shfl_xor(v, 16);
        v += __shfl_xor(v, 32);
        if (quad == 0 && col < E_) atomicAdd(&wsum[col], v);   // LDS atomic
    }
    __syncthreads();

    // coalesced pT store + weight partial store
    #pragma unroll
    for (int j = 0; j < 2; j++){
        const int i = tid + 256*j;
        const int e = i >> 2;
        const int o = (i & 3) * 8;
        uint4 v = *(const uint4*)(spT + e*40 + o);
        *(uint4*)(pT + ((size_t)bb*EP_ + e)*T_ + tl0 + o) = v;
    }
    if (tid < 128) wpart[((size_t)bb*EP_ + (tl0 >> 5))*EP_ + tid] = wsum[tid];
}

// ---------------- K3: partial entity_features (bf16 tokens) --------------------
// grid = (16 d-tiles, TC_ t-chunks, 8 batches) = 512 blocks. Tile 128e x 64d.
__global__ __launch_bounds__(256) void k_feat(const unsigned short* __restrict__ tb,
                                              const unsigned short* __restrict__ pT,
                                              float* __restrict__ facc_part){
    const int tid = threadIdx.x;
    const int d0  = blockIdx.x * 64;
    const int tc  = blockIdx.y;
    const int bb  = blockIdx.z;
    const int KT  = T_ / TC_;       // 1024

    __shared__ __align__(16) unsigned short lds_a[128*72];   // [e][t]
    __shared__ __align__(16) unsigned short lds_bt[64*72];   // [d][t]

    const unsigned short* gA[4]; unsigned short* sA[4];
    #pragma unroll
    for (int j = 0; j < 4; j++){
        int row = (tid >> 3) + 32*j;
        gA[j] = pT + ((size_t)bb*EP_ + row)*T_ + tc*KT + (tid & 7)*8;
        sA[j] = lds_a + row*72 + (tid & 7)*8;
    }
    const int trow = tid >> 2, dseg = tid & 3;
    const unsigned short* gB = tb + ((size_t)(bb*T_ + tc*KT + trow))*D_ + d0 + dseg*16;

    const int lane = tid & 63, w = tid >> 6;
    const int wm = w >> 1, wn = w & 1, lrow = lane & 15, quad = lane >> 4;

    f32x4 acc[4][2];
    #pragma unroll
    for (int i = 0; i < 4; i++)
        #pragma unroll
        for (int j = 0; j < 2; j++) acc[i][j] = (f32x4){0.f,0.f,0.f,0.f};

    for (int kt0 = 0; kt0 < KT; kt0 += 64){
        #pragma unroll
        for (int j = 0; j < 4; j++)
            *(uint4*)(sA[j]) = *(const uint4*)(gA[j] + kt0);
        {
            uint4 u0 = *(const uint4*)(gB + (size_t)kt0*D_);
            uint4 u1 = *(const uint4*)(gB + (size_t)kt0*D_ + 8);
            const unsigned int uu[8] = {u0.x,u0.y,u0.z,u0.w,u1.x,u1.y,u1.z,u1.w};
            #pragma unroll
            for (int q = 0; q < 8; q++){
                int dloc = dseg*16 + q*2;
                lds_bt[(dloc+0)*72 + trow] = (unsigned short)(uu[q] & 0xffffu);
                lds_bt[(dloc+1)*72 + trow] = (unsigned short)(uu[q] >> 16);
            }
        }
        __syncthreads();
        #pragma unroll
        for (int kk = 0; kk < 64; kk += 32){
            bf16x8 af[4], bfr[2];
            #pragma unroll
            for (int mi = 0; mi < 4; mi++)
                af[mi] = *(const bf16x8*)(lds_a + (wm*64 + mi*16 + lrow)*72 + kk + quad*8);
            #pragma unroll
            for (int ni = 0; ni < 2; ni++)
                bfr[ni] = *(const bf16x8*)(lds_bt + (wn*32 + ni*16 + lrow)*72 + kk + quad*8);
            #pragma unroll
            for (int mi = 0; mi < 4; mi++)
                #pragma unroll
                for (int ni = 0; ni < 2; ni++)
                    acc[mi][ni] = __builtin_amdgcn_mfma_f32_16x16x32_bf16(af[mi], bfr[ni], acc[mi][ni], 0, 0, 0);
        }
        __syncthreads();
    }

    #pragma unroll
    for (int mi = 0; mi < 4; mi++){
        #pragma unroll
        for (int ni = 0; ni < 2; ni++){
            int d = d0 + wn*32 + ni*16 + lrow;
            #pragma unroll
            for (int rr = 0; rr < 4; rr++){
                int e = wm*64 + mi*16 + quad*4 + rr;
                if (e < E_)
                    facc_part[((size_t)(tc*B_ + bb)*E_ + e)*D_ + d] = acc[mi][ni][rr];
            }
        }
    }
}

// ---------------- K4: w = sum chunks; out = (sum parts)/(w+eps) ----------------
// grid = (E_, B_), 256 threads.
__global__ __launch_bounds__(256) void k_final(const float* __restrict__ wpart,
                                               const float* __restrict__ facc_part,
                                               float* __restrict__ out_feat){
    const int e  = blockIdx.x;
    const int bb = blockIdx.y;
    const int tid = threadIdx.x;

    __shared__ float red[128];
    if (tid < 128) red[tid] = wpart[((size_t)bb*EP_ + tid)*EP_ + e];
    __syncthreads();
    for (int st = 64; st > 0; st >>= 1){ if (tid < st) red[tid] += red[tid+st]; __syncthreads(); }
    const float winv = 1.0f / (red[0] + 1e-6f);

    const int d = tid * 4;
    float4 o = make_float4(0.f, 0.f, 0.f, 0.f);
    #pragma unroll
    for (int tc = 0; tc < TC_; tc++){
        float4 p = *(const float4*)(facc_part + ((size_t)(tc*B_ + bb)*E_ + e)*D_ + d);
        o.x += p.x; o.y += p.y; o.z += p.z; o.w += p.w;
    }
    o.x *= winv; o.y *= winv; o.z *= winv; o.w *= winv;
    *(float4*)(out_feat + ((size_t)bb*E_ + e)*D_ + d) = o;
}

extern "C" void kernel_launch(void* const* d_in, const int* in_sizes, int n_in,
                              void* d_out, int out_size, void* d_ws, size_t ws_size,
                              hipStream_t stream){
    const float* tokens = (const float*)d_in[0];
    const float* cent   = (const float*)d_in[1];
    float* out        = (float*)d_out;
    float* out_assign = out;
    float* out_feat   = out + (size_t)B_*T_*E_;

    unsigned short* tb = (unsigned short*)d_ws;                       // 64 MB bf16 tokens
    float* norms = (float*)(tb + (size_t)NTOK*D_);                    // NTOK f32
    float* wpart = norms + NTOK;                                      // B*128*128 f32
    float* facc_part = wpart + (size_t)B_*EP_*EP_;                    // TC_*B*E*D f32
    unsigned short* cn = (unsigned short*)(facc_part + (size_t)TC_*B_*E_*D_);  // EP_*D_ bf16
    unsigned short* pT = cn + (size_t)EP_*D_;                         // B_*EP_*T_ bf16

    k_prep <<<NTOK/4, 256, 0, stream>>>(tokens, tb, norms);
    k_cnorm<<<EP_, 256, 0, stream>>>(cent, cn);
    k_sim  <<<NTOK/32, 256, 0, stream>>>(tb, cn, norms, out_assign, pT, wpart);
    k_feat <<<dim3(16, TC_, B_), 256, 0, stream>>>(tb, pT, facc_part);
    k_final<<<dim3(E_, B_), 256, 0, stream>>>(wpart, facc_part, out_feat);
}